// Round 13
// baseline (143.495 us; speedup 1.0000x reference)
//
#include <hip/hip_runtime.h>
#include <math.h>

#define NNODES 50000
#define NEDGES 800000
#define HIDDEN 128
#define NH 8
#define CAP 64            // max in-degree; Binomial(8e5,1/5e4) max ~35, P(>=64) negligible
#define NPART 8           // dst partitions ~ XCDs
#define PART_SZ 6250      // 50000/8
#define SCAT_BPP 128      // blocks per partition
#define SCAT_BLOCKS (NPART * SCAT_BPP)   // 1024
#define QKV_WAVES 1563    // ceil(50000 rows / 32 rows per wave)
#define QKV_BLOCKS 391    // ceil(1563/4)

typedef __bf16 bf16x8 __attribute__((ext_vector_type(8)));
typedef float  f32x4  __attribute__((ext_vector_type(4)));

// RNE float -> bf16 bits
__device__ inline unsigned short f2b(float f) {
    unsigned u = __float_as_uint(f);
    unsigned r = (u + 0x7fffu + ((u >> 16) & 1u)) >> 16;
    return (unsigned short)r;
}

// load 8 consecutive fp32 -> one bf16x8 MFMA fragment
__device__ inline bf16x8 ld_a8(const float* __restrict__ p) {
    float4 a = *(const float4*)p;
    float4 b = *(const float4*)(p + 4);
    bf16x8 r;
    r[0] = (__bf16)a.x; r[1] = (__bf16)a.y; r[2] = (__bf16)a.z; r[3] = (__bf16)a.w;
    r[4] = (__bf16)b.x; r[5] = (__bf16)b.y; r[6] = (__bf16)b.z; r[7] = (__bf16)b.w;
    return r;
}

// unpack 8 bf16 (4 dwords) -> 8 fp32
__device__ inline void up8(const uint4 u, float* f) {
    f[0] = __uint_as_float(u.x << 16); f[1] = __uint_as_float(u.x & 0xffff0000u);
    f[2] = __uint_as_float(u.y << 16); f[3] = __uint_as_float(u.y & 0xffff0000u);
    f[4] = __uint_as_float(u.z << 16); f[5] = __uint_as_float(u.z & 0xffff0000u);
    f[6] = __uint_as_float(u.w << 16); f[7] = __uint_as_float(u.w & 0xffff0000u);
}

// ---- pack weights into MFMA fragment order + zero cnt (fat) ----
__global__ __launch_bounds__(256)
void pack_init(const float* __restrict__ Wq, const float* __restrict__ Wk,
               const float* __restrict__ Wv, const float* __restrict__ Wo,
               unsigned short* __restrict__ Pqkv, unsigned short* __restrict__ Po,
               int* __restrict__ cnt)
{
    if (blockIdx.x >= 32) {
        const int idx = (blockIdx.x - 32) * 256 + threadIdx.x;   // int4 index
        if (idx < NNODES / 4) ((int4*)cnt)[idx] = make_int4(0, 0, 0, 0);
        return;
    }
    const int s = blockIdx.x * 4 + (threadIdx.x >> 6);   // 0..127
    const int lane = threadIdx.x & 63;
    const float* W; unsigned short* P; int ct, c;
    if (s < 96) { ct = s >> 2; c = s & 3;
        W = (ct < 8) ? Wq : (ct < 16) ? Wk : Wv;
        P = Pqkv + (size_t)s * 512;
        ct &= 7;
    } else { int t = s - 96; ct = t >> 2; c = t & 3; W = Wo; P = Po + (size_t)t * 512; }
    const int colin = ct * 16 + (lane & 15);
    const int k0 = c * 32 + (lane >> 4) * 8;
    const float* sp = W + (size_t)colin * 128 + k0;
    unsigned short v[8];
#pragma unroll
    for (int j = 0; j < 8; ++j) v[j] = f2b(sp[j]);
    uint4 o;
    o.x = (unsigned)v[0] | ((unsigned)v[1] << 16);
    o.y = (unsigned)v[2] | ((unsigned)v[3] << 16);
    o.z = (unsigned)v[4] | ((unsigned)v[5] << 16);
    o.w = (unsigned)v[6] | ((unsigned)v[7] << 16);
    *(uint4*)(P + lane * 8) = o;
}

// ---- Fat kernel: QKV projection (2 bands = 32 rows per wave) + bucketing ----
// lane (ar=lane&15, kg=lane>>4) holds C[rowbase+kg*4+j][t*16+ar] per band.
// KVb row layout: [K 128 bf16 | V 128 bf16] = 512B per node.
__global__ __launch_bounds__(256)
void qkv_scatter(const float* __restrict__ x, const unsigned short* __restrict__ Pqkv,
                 const float* __restrict__ bq, const float* __restrict__ bk,
                 const float* __restrict__ bv,
                 const int* __restrict__ src, const int* __restrict__ dst,
                 unsigned short* __restrict__ Qb, unsigned short* __restrict__ KVb,
                 int* __restrict__ cnt, int* __restrict__ bucket)
{
    if (blockIdx.x >= QKV_BLOCKS) {
        const int sb = blockIdx.x - QKV_BLOCKS;
        const int part = sb & (NPART - 1);
        const int blk  = sb >> 3;              // 0..SCAT_BPP-1
        const int lo = part * PART_SZ, hi = lo + PART_SZ;
        for (int e = blk * 256 + threadIdx.x; e < NEDGES; e += SCAT_BPP * 256) {
            const int d = dst[e];
            if (d >= lo && d < hi) {
                const int pos = atomicAdd(&cnt[d], 1);
                if (pos < CAP) bucket[d * CAP + pos] = src[e];
            }
        }
        return;
    }

    const int w = blockIdx.x * 4 + (threadIdx.x >> 6);
    if (w >= QKV_WAVES) return;
    const int lane = threadIdx.x & 63;
    const int row0 = w * 32;
    const int ar = lane & 15, kg = lane >> 4;
    const bool two = (row0 + 16) < NNODES;     // last wave has only band 0

    const float* ap0 = x + (size_t)(row0 + ar) * 128 + kg * 8;
    const float* ap1 = two ? (ap0 + 16 * 128) : ap0;
    const bf16x8 a00 = ld_a8(ap0), a01 = ld_a8(ap0 + 32), a02 = ld_a8(ap0 + 64), a03 = ld_a8(ap0 + 96);
    const bf16x8 a10 = ld_a8(ap1), a11 = ld_a8(ap1 + 32), a12 = ld_a8(ap1 + 64), a13 = ld_a8(ap1 + 96);

    const unsigned short* wp = Pqkv + lane * 8;
    bf16x8 nb0 = *(const bf16x8*)(wp);
    bf16x8 nb1 = *(const bf16x8*)(wp + 512);
    bf16x8 nb2 = *(const bf16x8*)(wp + 1024);
    bf16x8 nb3 = *(const bf16x8*)(wp + 1536);

#pragma unroll
    for (int t = 0; t < 24; ++t) {
        const bf16x8 b0 = nb0, b1 = nb1, b2 = nb2, b3 = nb3;
        if (t < 23) {
            const unsigned short* nw = wp + (size_t)(t + 1) * 2048;
            nb0 = *(const bf16x8*)(nw);
            nb1 = *(const bf16x8*)(nw + 512);
            nb2 = *(const bf16x8*)(nw + 1024);
            nb3 = *(const bf16x8*)(nw + 1536);
        }
        f32x4 acc0 = {0.f, 0.f, 0.f, 0.f};
        f32x4 acc1 = {0.f, 0.f, 0.f, 0.f};
        acc0 = __builtin_amdgcn_mfma_f32_16x16x32_bf16(a00, b0, acc0, 0, 0, 0);
        acc1 = __builtin_amdgcn_mfma_f32_16x16x32_bf16(a10, b0, acc1, 0, 0, 0);
        acc0 = __builtin_amdgcn_mfma_f32_16x16x32_bf16(a01, b1, acc0, 0, 0, 0);
        acc1 = __builtin_amdgcn_mfma_f32_16x16x32_bf16(a11, b1, acc1, 0, 0, 0);
        acc0 = __builtin_amdgcn_mfma_f32_16x16x32_bf16(a02, b2, acc0, 0, 0, 0);
        acc1 = __builtin_amdgcn_mfma_f32_16x16x32_bf16(a12, b2, acc1, 0, 0, 0);
        acc0 = __builtin_amdgcn_mfma_f32_16x16x32_bf16(a03, b3, acc0, 0, 0, 0);
        acc1 = __builtin_amdgcn_mfma_f32_16x16x32_bf16(a13, b3, acc1, 0, 0, 0);

        const int sel = t >> 3;               // 0=Q 1=K 2=V
        const int colin = (t & 7) * 16 + ar;
        if (sel == 0) {
            const float bsc = bq[colin];
#pragma unroll
            for (int j = 0; j < 4; ++j)
                Qb[(size_t)(row0 + kg * 4 + j) * 128 + colin] = f2b(acc0[j] + bsc);
            if (two) {
#pragma unroll
                for (int j = 0; j < 4; ++j)
                    Qb[(size_t)(row0 + 16 + kg * 4 + j) * 128 + colin] = f2b(acc1[j] + bsc);
            }
        } else {
            const int vo = (sel == 2) ? 128 : 0;
            const float bsc = (sel == 1) ? bk[colin] : bv[colin];
#pragma unroll
            for (int j = 0; j < 4; ++j)
                KVb[(size_t)(row0 + kg * 4 + j) * 256 + vo + colin] = f2b(acc0[j] + bsc);
            if (two) {
#pragma unroll
                for (int j = 0; j < 4; ++j)
                    KVb[(size_t)(row0 + 16 + kg * 4 + j) * 256 + vo + colin] = f2b(acc1[j] + bsc);
            }
        }
    }
}

// ---- Fused attention + output projection ----
// Block = 16 consecutive nodes; wave handles 4 (sequential). Per node:
// lane = (head h, slot); 8 edges in parallel; (m,s) butterfly then
// per-lane scale + tree-SUM of o (cheap merge). Results go to LDS,
// then the block does the 16-row output projection from LDS.
__global__ __launch_bounds__(256)
void attn_outproj(const unsigned short* __restrict__ Qb,
                  const unsigned short* __restrict__ KVb,
                  const int* __restrict__ cnt, const int* __restrict__ bucket,
                  const unsigned short* __restrict__ Po,
                  const float* __restrict__ bo, float* __restrict__ out)
{
    __shared__ __align__(16) unsigned short accs[16][136];   // +8 pad vs 128
    const int wave = threadIdx.x >> 6;
    const int lane = threadIdx.x & 63;
    const int h = lane >> 3;      // head 0..7
    const int slot = lane & 7;    // edge slot 0..7
    const int nb0 = blockIdx.x * 16;

    for (int nl = 0; nl < 4; ++nl) {
        const int n = nb0 + wave * 4 + nl;

        int deg = cnt[n]; deg = deg > CAP ? CAP : deg;
        const int mysrc = (lane < deg) ? bucket[n * CAP + lane] : 0;

        // q[16] for this head, pre-scaled by D^-0.5
        float q[16];
        {
            const uint4* qp = (const uint4*)(Qb + (size_t)n * HIDDEN + h * 16);
            up8(qp[0], q); up8(qp[1], q + 8);
#pragma unroll
            for (int j = 0; j < 16; ++j) q[j] *= 0.25f;
        }

        float m = -1e30f, s = 0.f;
        float o[16];
#pragma unroll
        for (int j = 0; j < 16; ++j) o[j] = 0.f;

        const int nit = (deg + 7) >> 3;
        const uint4 zz = make_uint4(0, 0, 0, 0);
        uint4 k0 = zz, k1 = zz, v0 = zz, v1 = zz;
        if (slot < deg) {
            const int sid = __shfl(mysrc, slot);
            const uint4* kp = (const uint4*)(KVb + (size_t)sid * 256 + h * 16);
            k0 = kp[0]; k1 = kp[1];
            const uint4* vp = (const uint4*)(KVb + (size_t)sid * 256 + 128 + h * 16);
            v0 = vp[0]; v1 = vp[1];
        }

        for (int i = 0; i < nit; ++i) {
            uint4 nk0 = zz, nk1 = zz, nv0 = zz, nv1 = zz;
            const int nidx = i * 8 + 8 + slot;
            if (nidx < deg) {
                const int sid = __shfl(mysrc, nidx);
                const uint4* kp = (const uint4*)(KVb + (size_t)sid * 256 + h * 16);
                nk0 = kp[0]; nk1 = kp[1];
                const uint4* vp = (const uint4*)(KVb + (size_t)sid * 256 + 128 + h * 16);
                nv0 = vp[0]; nv1 = vp[1];
            }
            float kk[16], vv[16];
            up8(k0, kk); up8(k1, kk + 8);
            up8(v0, vv); up8(v1, vv + 8);

            float d0 = 0.f, d1 = 0.f, d2 = 0.f, d3 = 0.f;
#pragma unroll
            for (int j = 0; j < 16; j += 4) {
                d0 = fmaf(q[j],     kk[j],     d0);
                d1 = fmaf(q[j + 1], kk[j + 1], d1);
                d2 = fmaf(q[j + 2], kk[j + 2], d2);
                d3 = fmaf(q[j + 3], kk[j + 3], d3);
            }
            float score = (d0 + d1) + (d2 + d3);
            if (i * 8 + slot >= deg) score = -2e30f;   // inactive slot

            const float dd = score - m;
            const float em = __expf(-fabsf(dd));
            const bool nm = dd > 0.f;
            const float so = nm ? em : 1.f;
            const float pp = nm ? 1.f : em;
            m = nm ? score : m;
            s = fmaf(s, so, pp);
#pragma unroll
            for (int j = 0; j < 16; ++j)
                o[j] = fmaf(o[j], so, pp * vv[j]);

            k0 = nk0; k1 = nk1; v0 = nv0; v1 = nv1;
        }

        // butterfly merge of (m,s) only (masks 1/2/4 within the head's 8 slots)
        float mt = m, st = s;
#pragma unroll
        for (int mask = 1; mask <= 4; mask <<= 1) {
            const float om = __shfl_xor(mt, mask);
            const float os = __shfl_xor(st, mask);
            const float dd = om - mt;
            const float em = __expf(-fabsf(dd));
            const bool nm = dd > 0.f;
            const float so = nm ? em : 1.f;
            const float oo = nm ? 1.f : em;
            mt = nm ? om : mt;
            st = fmaf(st, so, os * oo);
        }
        // per-lane normalize, then pure tree-sum of o
        const float scale = __expf(m - mt) / (st + 1e-12f);
#pragma unroll
        for (int j = 0; j < 16; ++j) o[j] *= scale;
#pragma unroll
        for (int mask = 1; mask <= 4; mask <<= 1) {
#pragma unroll
            for (int j = 0; j < 16; ++j) o[j] += __shfl_xor(o[j], mask);
        }

        if (slot == 0) {
            const int nloc = wave * 4 + nl;
            uint4 w0, w1;
            w0.x = (unsigned)f2b(o[0])  | ((unsigned)f2b(o[1])  << 16);
            w0.y = (unsigned)f2b(o[2])  | ((unsigned)f2b(o[3])  << 16);
            w0.z = (unsigned)f2b(o[4])  | ((unsigned)f2b(o[5])  << 16);
            w0.w = (unsigned)f2b(o[6])  | ((unsigned)f2b(o[7])  << 16);
            w1.x = (unsigned)f2b(o[8])  | ((unsigned)f2b(o[9])  << 16);
            w1.y = (unsigned)f2b(o[10]) | ((unsigned)f2b(o[11]) << 16);
            w1.z = (unsigned)f2b(o[12]) | ((unsigned)f2b(o[13]) << 16);
            w1.w = (unsigned)f2b(o[14]) | ((unsigned)f2b(o[15]) << 16);
            *(uint4*)&accs[nloc][h * 16]     = w0;
            *(uint4*)&accs[nloc][h * 16 + 8] = w1;
        }
    }
    __syncthreads();

    // ---- output projection for this block's 16 rows (A from LDS) ----
    const int ar = lane & 15, kg = lane >> 4;
    const unsigned short* ab = &accs[ar][kg * 8];
    const bf16x8 a0 = *(const bf16x8*)(ab);
    const bf16x8 a1 = *(const bf16x8*)(ab + 32);
    const bf16x8 a2 = *(const bf16x8*)(ab + 64);
    const bf16x8 a3 = *(const bf16x8*)(ab + 96);

    const unsigned short* wp = Po + lane * 8;
    bf16x8 pb0 = *(const bf16x8*)(wp);
    bf16x8 pb1 = *(const bf16x8*)(wp + 512);
    bf16x8 pb2 = *(const bf16x8*)(wp + 1024);
    bf16x8 pb3 = *(const bf16x8*)(wp + 1536);

#pragma unroll
    for (int t = 0; t < 8; ++t) {
        const bf16x8 b0 = pb0, b1 = pb1, b2 = pb2, b3 = pb3;
        if (t < 7) {
            const unsigned short* nw = wp + (size_t)(t + 1) * 2048;
            pb0 = *(const bf16x8*)(nw);
            pb1 = *(const bf16x8*)(nw + 512);
            pb2 = *(const bf16x8*)(nw + 1024);
            pb3 = *(const bf16x8*)(nw + 1536);
        }
        f32x4 acc = {0.f, 0.f, 0.f, 0.f};
        acc = __builtin_amdgcn_mfma_f32_16x16x32_bf16(a0, b0, acc, 0, 0, 0);
        acc = __builtin_amdgcn_mfma_f32_16x16x32_bf16(a1, b1, acc, 0, 0, 0);
        acc = __builtin_amdgcn_mfma_f32_16x16x32_bf16(a2, b2, acc, 0, 0, 0);
        acc = __builtin_amdgcn_mfma_f32_16x16x32_bf16(a3, b3, acc, 0, 0, 0);

        const int colin = t * 16 + ar;
        const float bsc = bo[colin];
#pragma unroll
        for (int j = 0; j < 4; ++j)
            out[(size_t)(nb0 + kg * 4 + j) * 128 + colin] = acc[j] + bsc;
    }
}

extern "C" void kernel_launch(void* const* d_in, const int* in_sizes, int n_in,
                              void* d_out, int out_size, void* d_ws, size_t ws_size,
                              hipStream_t stream) {
    const float* x  = (const float*)d_in[0];
    const int*   ei = (const int*)d_in[1];      // (2, E) int32: [0]=src, [1]=dst
    const int*   src = ei;
    const int*   dst = ei + NEDGES;
    const float* Wq = (const float*)d_in[3];
    const float* bq = (const float*)d_in[4];
    const float* Wk = (const float*)d_in[5];
    const float* bk = (const float*)d_in[6];
    const float* Wv = (const float*)d_in[7];
    const float* bv = (const float*)d_in[8];
    const float* Wo = (const float*)d_in[9];
    const float* bo = (const float*)d_in[10];
    float* out = (float*)d_out;

    // workspace layout (all offsets 16B-aligned)
    char* ws = (char*)d_ws;
    size_t off = 0;
    const size_t sz_nhb = (size_t)NNODES * HIDDEN * sizeof(unsigned short); // 12.8 MB
    unsigned short* Qb     = (unsigned short*)(ws + off); off += sz_nhb;
    unsigned short* KVb    = (unsigned short*)(ws + off); off += 2 * sz_nhb;
    unsigned short* Pqkv   = (unsigned short*)(ws + off); off += 96 * 512 * sizeof(unsigned short);
    unsigned short* Po     = (unsigned short*)(ws + off); off += 32 * 512 * sizeof(unsigned short);
    int*            cnt    = (int*)(ws + off);            off += (size_t)NNODES * sizeof(int);
    int*            bucket = (int*)(ws + off);            off += (size_t)NNODES * CAP * sizeof(int);

    // 32 pack blocks + 49 cnt-zero blocks
    pack_init<<<81, 256, 0, stream>>>(Wq, Wk, Wv, Wo, Pqkv, Po, cnt);

    // fat: 391 qkv blocks (2-band waves) + 1024 scatter blocks
    qkv_scatter<<<QKV_BLOCKS + SCAT_BLOCKS, 256, 0, stream>>>(
        x, Pqkv, bq, bk, bv, src, dst, Qb, KVb, cnt, bucket);

    // 3125 blocks x 16 nodes, attention + fused output projection
    attn_outproj<<<3125, 256, 0, stream>>>(Qb, KVb, cnt, bucket, Po, bo, out);
}

// Round 14
// 133.585 us; speedup vs baseline: 1.0742x; 1.0742x over previous
//
#include <hip/hip_runtime.h>
#include <math.h>

#define NNODES 50000
#define NEDGES 800000
#define HIDDEN 128
#define NH 8
#define CAP 64            // max in-degree; Binomial(8e5,1/5e4) max ~35, P(>=64) negligible
#define NPART 8           // dst partitions ~ XCDs
#define PART_SZ 6250      // 50000/8
#define SCAT_BPP 128      // blocks per partition
#define SCAT_BLOCKS (NPART * SCAT_BPP)   // 1024
#define QKV_WAVES 1563    // ceil(50000 rows / 32 rows per wave)
#define QKV_BLOCKS 391    // ceil(1563/4)

typedef __bf16 bf16x8 __attribute__((ext_vector_type(8)));
typedef float  f32x4  __attribute__((ext_vector_type(4)));

// RNE float -> bf16 bits
__device__ inline unsigned short f2b(float f) {
    unsigned u = __float_as_uint(f);
    unsigned r = (u + 0x7fffu + ((u >> 16) & 1u)) >> 16;
    return (unsigned short)r;
}

// load 8 consecutive fp32 -> one bf16x8 MFMA fragment
__device__ inline bf16x8 ld_a8(const float* __restrict__ p) {
    float4 a = *(const float4*)p;
    float4 b = *(const float4*)(p + 4);
    bf16x8 r;
    r[0] = (__bf16)a.x; r[1] = (__bf16)a.y; r[2] = (__bf16)a.z; r[3] = (__bf16)a.w;
    r[4] = (__bf16)b.x; r[5] = (__bf16)b.y; r[6] = (__bf16)b.z; r[7] = (__bf16)b.w;
    return r;
}

// ---- pack weights into MFMA fragment order + zero cnt (fat) ----
__global__ __launch_bounds__(256)
void pack_init(const float* __restrict__ Wq, const float* __restrict__ Wk,
               const float* __restrict__ Wv, const float* __restrict__ Wo,
               unsigned short* __restrict__ Pqkv, unsigned short* __restrict__ Po,
               int* __restrict__ cnt)
{
    if (blockIdx.x >= 32) {
        const int idx = (blockIdx.x - 32) * 256 + threadIdx.x;   // int4 index
        if (idx < NNODES / 4) ((int4*)cnt)[idx] = make_int4(0, 0, 0, 0);
        return;
    }
    const int s = blockIdx.x * 4 + (threadIdx.x >> 6);   // 0..127
    const int lane = threadIdx.x & 63;
    const float* W; unsigned short* P; int ct, c;
    if (s < 96) { ct = s >> 2; c = s & 3;
        W = (ct < 8) ? Wq : (ct < 16) ? Wk : Wv;
        P = Pqkv + (size_t)s * 512;
        ct &= 7;
    } else { int t = s - 96; ct = t >> 2; c = t & 3; W = Wo; P = Po + (size_t)t * 512; }
    const int colin = ct * 16 + (lane & 15);
    const int k0 = c * 32 + (lane >> 4) * 8;
    const float* sp = W + (size_t)colin * 128 + k0;
    unsigned short v[8];
#pragma unroll
    for (int j = 0; j < 8; ++j) v[j] = f2b(sp[j]);
    uint4 o;
    o.x = (unsigned)v[0] | ((unsigned)v[1] << 16);
    o.y = (unsigned)v[2] | ((unsigned)v[3] << 16);
    o.z = (unsigned)v[4] | ((unsigned)v[5] << 16);
    o.w = (unsigned)v[6] | ((unsigned)v[7] << 16);
    *(uint4*)(P + lane * 8) = o;
}

// ---- Fat kernel: QKV projection (2 bands = 32 rows per wave) + bucketing ----
// lane (ar=lane&15, kg=lane>>4) holds C[rowbase+kg*4+j][t*16+ar] per band.
// KVb pairwise layout: {K[2l],K[2l+1],V[2l],V[2l+1]} at node*256 + 4l (shorts).
__global__ __launch_bounds__(256)
void qkv_scatter(const float* __restrict__ x, const unsigned short* __restrict__ Pqkv,
                 const float* __restrict__ bq, const float* __restrict__ bk,
                 const float* __restrict__ bv,
                 const int* __restrict__ src, const int* __restrict__ dst,
                 unsigned short* __restrict__ Qb, unsigned short* __restrict__ KVb,
                 int* __restrict__ cnt, int* __restrict__ bucket)
{
    if (blockIdx.x >= QKV_BLOCKS) {
        const int sb = blockIdx.x - QKV_BLOCKS;
        const int part = sb & (NPART - 1);
        const int blk  = sb >> 3;              // 0..SCAT_BPP-1
        const int lo = part * PART_SZ, hi = lo + PART_SZ;
        for (int e = blk * 256 + threadIdx.x; e < NEDGES; e += SCAT_BPP * 256) {
            const int d = dst[e];
            if (d >= lo && d < hi) {
                const int pos = atomicAdd(&cnt[d], 1);
                if (pos < CAP) bucket[d * CAP + pos] = src[e];
            }
        }
        return;
    }

    const int w = blockIdx.x * 4 + (threadIdx.x >> 6);
    if (w >= QKV_WAVES) return;
    const int lane = threadIdx.x & 63;
    const int row0 = w * 32;
    const int ar = lane & 15, kg = lane >> 4;
    const bool two = (row0 + 16) < NNODES;     // last wave has only band 0

    const float* ap0 = x + (size_t)(row0 + ar) * 128 + kg * 8;
    const float* ap1 = two ? (ap0 + 16 * 128) : ap0;
    const bf16x8 a00 = ld_a8(ap0), a01 = ld_a8(ap0 + 32), a02 = ld_a8(ap0 + 64), a03 = ld_a8(ap0 + 96);
    const bf16x8 a10 = ld_a8(ap1), a11 = ld_a8(ap1 + 32), a12 = ld_a8(ap1 + 64), a13 = ld_a8(ap1 + 96);

    const unsigned short* wp = Pqkv + lane * 8;
    bf16x8 nb0 = *(const bf16x8*)(wp);
    bf16x8 nb1 = *(const bf16x8*)(wp + 512);
    bf16x8 nb2 = *(const bf16x8*)(wp + 1024);
    bf16x8 nb3 = *(const bf16x8*)(wp + 1536);

#pragma unroll
    for (int t = 0; t < 24; ++t) {
        const bf16x8 b0 = nb0, b1 = nb1, b2 = nb2, b3 = nb3;
        if (t < 23) {
            const unsigned short* nw = wp + (size_t)(t + 1) * 2048;
            nb0 = *(const bf16x8*)(nw);
            nb1 = *(const bf16x8*)(nw + 512);
            nb2 = *(const bf16x8*)(nw + 1024);
            nb3 = *(const bf16x8*)(nw + 1536);
        }
        f32x4 acc0 = {0.f, 0.f, 0.f, 0.f};
        f32x4 acc1 = {0.f, 0.f, 0.f, 0.f};
        acc0 = __builtin_amdgcn_mfma_f32_16x16x32_bf16(a00, b0, acc0, 0, 0, 0);
        acc1 = __builtin_amdgcn_mfma_f32_16x16x32_bf16(a10, b0, acc1, 0, 0, 0);
        acc0 = __builtin_amdgcn_mfma_f32_16x16x32_bf16(a01, b1, acc0, 0, 0, 0);
        acc1 = __builtin_amdgcn_mfma_f32_16x16x32_bf16(a11, b1, acc1, 0, 0, 0);
        acc0 = __builtin_amdgcn_mfma_f32_16x16x32_bf16(a02, b2, acc0, 0, 0, 0);
        acc1 = __builtin_amdgcn_mfma_f32_16x16x32_bf16(a12, b2, acc1, 0, 0, 0);
        acc0 = __builtin_amdgcn_mfma_f32_16x16x32_bf16(a03, b3, acc0, 0, 0, 0);
        acc1 = __builtin_amdgcn_mfma_f32_16x16x32_bf16(a13, b3, acc1, 0, 0, 0);

        const int sel = t >> 3;               // 0=Q 1=K 2=V
        const int colin = (t & 7) * 16 + ar;
        if (sel == 0) {
            const float bsc = bq[colin];
#pragma unroll
            for (int j = 0; j < 4; ++j)
                Qb[(size_t)(row0 + kg * 4 + j) * 128 + colin] = f2b(acc0[j] + bsc);
            if (two) {
#pragma unroll
                for (int j = 0; j < 4; ++j)
                    Qb[(size_t)(row0 + 16 + kg * 4 + j) * 128 + colin] = f2b(acc1[j] + bsc);
            }
        } else {
            const float bsc = (sel == 1) ? bk[colin] : bv[colin];
            const int cbase = (colin >> 1) * 4 + (colin & 1) + ((sel == 2) ? 2 : 0);
#pragma unroll
            for (int j = 0; j < 4; ++j)
                KVb[(size_t)(row0 + kg * 4 + j) * 256 + cbase] = f2b(acc0[j] + bsc);
            if (two) {
#pragma unroll
                for (int j = 0; j < 4; ++j)
                    KVb[(size_t)(row0 + 16 + kg * 4 + j) * 256 + cbase] = f2b(acc1[j] + bsc);
            }
        }
    }
}

// ---- Fused score + online softmax + aggregation, 1 wave / node ----
// pair-processed edges: two independent dot/reduce chains per iteration,
// pair-combined with 1 exp, then one online merge (1 exp) -> 1 exp/edge.
__global__ __launch_bounds__(256)
void fused_attn_kernel(const unsigned short* __restrict__ Qb,
                       const unsigned short* __restrict__ KVb,
                       const int* __restrict__ cnt, const int* __restrict__ bucket,
                       unsigned short* __restrict__ accumb)
{
    const int wave = threadIdx.x >> 6;
    const int lane = threadIdx.x & 63;
    const int n = blockIdx.x * 4 + wave;
    if (n >= NNODES) return;

    int deg = cnt[n];
    deg = deg > CAP ? CAP : deg;
    const int mysrc = (lane < deg) ? bucket[n * CAP + lane] : 0;

    const unsigned short* kvbase = KVb + lane * 4;

    // q pre-scaled by D^-0.5 so dot == score
    const unsigned qw = *(const unsigned*)(Qb + (size_t)n * HIDDEN + lane * 2);
    const float qx = __uint_as_float(qw << 16) * 0.25f;
    const float qy = __uint_as_float(qw & 0xffff0000u) * 0.25f;

    float m = -INFINITY, s = 0.f, ox = 0.f, oy = 0.f;

    // prefetch ring, depth 4
    uint2 kvA = make_uint2(0,0), kvB = kvA, kvC = kvA, kvD = kvA;
    if (deg > 0) kvA = *(const uint2*)(kvbase + ((size_t)__shfl(mysrc, 0) << 8));
    if (deg > 1) kvB = *(const uint2*)(kvbase + ((size_t)__shfl(mysrc, 1) << 8));
    if (deg > 2) kvC = *(const uint2*)(kvbase + ((size_t)__shfl(mysrc, 2) << 8));
    if (deg > 3) kvD = *(const uint2*)(kvbase + ((size_t)__shfl(mysrc, 3) << 8));

    int i = 0;
    for (; i + 2 <= deg; i += 2) {
        const uint2 c0 = kvA, c1 = kvB;
        kvA = kvC; kvB = kvD;
        if (i + 4 < deg) kvC = *(const uint2*)(kvbase + ((size_t)__shfl(mysrc, i + 4) << 8));
        if (i + 5 < deg) kvD = *(const uint2*)(kvbase + ((size_t)__shfl(mysrc, i + 5) << 8));

        // two independent score chains
        float d0 = qx * __uint_as_float(c0.x << 16) + qy * __uint_as_float(c0.x & 0xffff0000u);
        float d1 = qx * __uint_as_float(c1.x << 16) + qy * __uint_as_float(c1.x & 0xffff0000u);
        d0 += __shfl_xor(d0, 1);  d1 += __shfl_xor(d1, 1);
        d0 += __shfl_xor(d0, 2);  d1 += __shfl_xor(d1, 2);
        d0 += __shfl_xor(d0, 4);  d1 += __shfl_xor(d1, 4);

        // pair combine: 1 exp
        const float pm = fmaxf(d0, d1);
        const float ee = __expf(-fabsf(d0 - d1));
        const bool g = d0 >= d1;
        const float v0x = __uint_as_float(c0.y << 16), v0y = __uint_as_float(c0.y & 0xffff0000u);
        const float v1x = __uint_as_float(c1.y << 16), v1y = __uint_as_float(c1.y & 0xffff0000u);
        const float sp  = 1.f + ee;
        const float ovx = fmaf(ee, g ? v1x : v0x, g ? v0x : v1x);
        const float ovy = fmaf(ee, g ? v1y : v0y, g ? v0y : v1y);

        // online merge: 1 exp
        const float dd = pm - m;
        const float em = __expf(-fabsf(dd));
        const bool nm = dd > 0.f;
        const float so = nm ? em : 1.f;
        const float sn = nm ? 1.f : em;
        m = nm ? pm : m;
        s  = fmaf(s,  so, sp  * sn);
        ox = fmaf(ox, so, ovx * sn);
        oy = fmaf(oy, so, ovy * sn);
    }
    if (i < deg) {  // odd tail
        const uint2 c0 = kvA;
        float d0 = qx * __uint_as_float(c0.x << 16) + qy * __uint_as_float(c0.x & 0xffff0000u);
        d0 += __shfl_xor(d0, 1);
        d0 += __shfl_xor(d0, 2);
        d0 += __shfl_xor(d0, 4);
        const float vx = __uint_as_float(c0.y << 16), vy = __uint_as_float(c0.y & 0xffff0000u);
        const float dd = d0 - m;
        const float em = __expf(-fabsf(dd));
        const bool nm = dd > 0.f;
        const float so = nm ? em : 1.f;
        const float pp = nm ? 1.f : em;
        m = nm ? d0 : m;
        s  = fmaf(s,  so, pp);
        ox = fmaf(ox, so, pp * vx);
        oy = fmaf(oy, so, pp * vy);
    }
    const float inv = 1.f / (s + 1e-12f);
    ushort2 ob = { f2b(ox * inv), f2b(oy * inv) };
    *(ushort2*)(accumb + (size_t)n * HIDDEN + lane * 2) = ob;
}

// ---- output projection: non-swapped mfma, pipelined B loads ----
__global__ __launch_bounds__(256)
void outproj_mfma(const unsigned short* __restrict__ accumb, const unsigned short* __restrict__ Po,
                  const float* __restrict__ bo, float* __restrict__ out)
{
    const int band = blockIdx.x * 4 + (threadIdx.x >> 6);
    if (band >= 3125) return;
    const int lane = threadIdx.x & 63;
    const int row0 = band * 16;
    const int ar = lane & 15, kg = lane >> 4;

    const unsigned short* ab = accumb + (size_t)(row0 + ar) * 128 + kg * 8;
    const bf16x8 a0 = *(const bf16x8*)(ab);
    const bf16x8 a1 = *(const bf16x8*)(ab + 32);
    const bf16x8 a2 = *(const bf16x8*)(ab + 64);
    const bf16x8 a3 = *(const bf16x8*)(ab + 96);

    const unsigned short* wp = Po + lane * 8;
    bf16x8 pb0 = *(const bf16x8*)(wp);
    bf16x8 pb1 = *(const bf16x8*)(wp + 512);
    bf16x8 pb2 = *(const bf16x8*)(wp + 1024);
    bf16x8 pb3 = *(const bf16x8*)(wp + 1536);

#pragma unroll
    for (int t = 0; t < 8; ++t) {
        const bf16x8 b0 = pb0, b1 = pb1, b2 = pb2, b3 = pb3;
        if (t < 7) {
            const unsigned short* nw = wp + (size_t)(t + 1) * 2048;
            pb0 = *(const bf16x8*)(nw);
            pb1 = *(const bf16x8*)(nw + 512);
            pb2 = *(const bf16x8*)(nw + 1024);
            pb3 = *(const bf16x8*)(nw + 1536);
        }
        f32x4 acc = {0.f, 0.f, 0.f, 0.f};
        acc = __builtin_amdgcn_mfma_f32_16x16x32_bf16(a0, b0, acc, 0, 0, 0);
        acc = __builtin_amdgcn_mfma_f32_16x16x32_bf16(a1, b1, acc, 0, 0, 0);
        acc = __builtin_amdgcn_mfma_f32_16x16x32_bf16(a2, b2, acc, 0, 0, 0);
        acc = __builtin_amdgcn_mfma_f32_16x16x32_bf16(a3, b3, acc, 0, 0, 0);

        const int colin = t * 16 + ar;
        const float bsc = bo[colin];
#pragma unroll
        for (int j = 0; j < 4; ++j)
            out[(size_t)(row0 + kg * 4 + j) * 128 + colin] = acc[j] + bsc;
    }
}

extern "C" void kernel_launch(void* const* d_in, const int* in_sizes, int n_in,
                              void* d_out, int out_size, void* d_ws, size_t ws_size,
                              hipStream_t stream) {
    const float* x  = (const float*)d_in[0];
    const int*   ei = (const int*)d_in[1];      // (2, E) int32: [0]=src, [1]=dst
    const int*   src = ei;
    const int*   dst = ei + NEDGES;
    const float* Wq = (const float*)d_in[3];
    const float* bq = (const float*)d_in[4];
    const float* Wk = (const float*)d_in[5];
    const float* bk = (const float*)d_in[6];
    const float* Wv = (const float*)d_in[7];
    const float* bv = (const float*)d_in[8];
    const float* Wo = (const float*)d_in[9];
    const float* bo = (const float*)d_in[10];
    float* out = (float*)d_out;

    // workspace layout (all offsets 16B-aligned)
    char* ws = (char*)d_ws;
    size_t off = 0;
    const size_t sz_nhb = (size_t)NNODES * HIDDEN * sizeof(unsigned short); // 12.8 MB
    unsigned short* Qb     = (unsigned short*)(ws + off); off += sz_nhb;
    unsigned short* KVb    = (unsigned short*)(ws + off); off += 2 * sz_nhb;
    unsigned short* accumb = (unsigned short*)(ws + off); off += sz_nhb;
    unsigned short* Pqkv   = (unsigned short*)(ws + off); off += 96 * 512 * sizeof(unsigned short);
    unsigned short* Po     = (unsigned short*)(ws + off); off += 32 * 512 * sizeof(unsigned short);
    int*            cnt    = (int*)(ws + off);            off += (size_t)NNODES * sizeof(int);
    int*            bucket = (int*)(ws + off);            off += (size_t)NNODES * CAP * sizeof(int);

    // 32 pack blocks + 49 cnt-zero blocks
    pack_init<<<81, 256, 0, stream>>>(Wq, Wk, Wv, Wo, Pqkv, Po, cnt);

    // fat: 391 qkv blocks (2-band waves) + 1024 scatter blocks
    qkv_scatter<<<QKV_BLOCKS + SCAT_BLOCKS, 256, 0, stream>>>(
        x, Pqkv, bq, bk, bv, src, dst, Qb, KVb, cnt, bucket);

    fused_attn_kernel<<<(NNODES + 3) / 4, 256, 0, stream>>>(Qb, KVb, cnt, bucket, accumb);

    outproj_mfma<<<782, 256, 0, stream>>>(accumb, Po, bo, out);
}